// Round 1
// baseline (54.643 us; speedup 1.0000x reference)
//
#include <hip/hip_runtime.h>
#include <math.h>

// Problem constants (from setup_inputs): B=4, N=2048 (unused — cancels), M=8192.
#define ICA_M     8192
#define ICA_BLOCK 256
#define ICA_VPT   (ICA_M / (ICA_BLOCK * 4))   // float4 vectors per thread = 8

// Algebraic reduction of the reference:
//   attn[b,i,j] = softmax_j(-(Q2_i + K2_j)) = softmax_j(-K2_j)   (row-shift invariance)
//   context[b,i] = sum_j softmax_j(-K2_j) * K2_j                  (independent of i)
//   out[b] = mean_i context[b,i] = sum_j exp(-K2_j)*K2_j / sum_j exp(-K2_j)
// where K2_j = (x_j - mean(x))^2, x = all_atom_features[b,:,0].
__global__ __launch_bounds__(ICA_BLOCK) void
InvariantCrossAttention_39582418600293_kernel(const float* __restrict__ all_atom,
                                              float* __restrict__ out) {
    const int b   = blockIdx.x;
    const int tid = threadIdx.x;
    const float4* base = (const float4*)(all_atom + (size_t)b * ICA_M);

    // ---- pass 1 (registers): load 32 KB/block as float4, partial sum ----
    float4 v[ICA_VPT];
    float s = 0.f;
#pragma unroll
    for (int i = 0; i < ICA_VPT; ++i) {
        v[i] = base[tid + i * ICA_BLOCK];           // coalesced: lane-contiguous
        s += (v[i].x + v[i].y) + (v[i].z + v[i].w);
    }

    // block reduce s -> mean
    __shared__ float red[ICA_BLOCK / 64];
    __shared__ float s_mean;
#pragma unroll
    for (int off = 32; off > 0; off >>= 1) s += __shfl_down(s, off, 64);
    const int wave = tid >> 6, lane = tid & 63;
    if (lane == 0) red[wave] = s;
    __syncthreads();
    if (tid == 0) {
        float t = 0.f;
#pragma unroll
        for (int w = 0; w < ICA_BLOCK / 64; ++w) t += red[w];
        s_mean = t * (1.0f / (float)ICA_M);
    }
    __syncthreads();
    const float mean = s_mean;

    // ---- pass 2 (registers only): num/den of the softmax-weighted K2 ----
    float num = 0.f, den = 0.f;
#pragma unroll
    for (int i = 0; i < ICA_VPT; ++i) {
        float d0 = v[i].x - mean, d1 = v[i].y - mean,
              d2 = v[i].z - mean, d3 = v[i].w - mean;
        float k0 = d0 * d0, k1 = d1 * d1, k2 = d2 * d2, k3 = d3 * d3;
        float e0 = __expf(-k0), e1 = __expf(-k1),
              e2 = __expf(-k2), e3 = __expf(-k3);
        den += (e0 + e1) + (e2 + e3);
        num += (e0 * k0 + e1 * k1) + (e2 * k2 + e3 * k3);
    }

    // block reduce (num, den) together
#pragma unroll
    for (int off = 32; off > 0; off >>= 1) {
        num += __shfl_down(num, off, 64);
        den += __shfl_down(den, off, 64);
    }
    __shared__ float rnum[ICA_BLOCK / 64], rden[ICA_BLOCK / 64];
    if (lane == 0) { rnum[wave] = num; rden[wave] = den; }
    __syncthreads();
    if (tid == 0) {
        float tn = 0.f, td = 0.f;
#pragma unroll
        for (int w = 0; w < ICA_BLOCK / 64; ++w) { tn += rnum[w]; td += rden[w]; }
        out[b] = tn / td;
    }
}

extern "C" void kernel_launch(void* const* d_in, const int* in_sizes, int n_in,
                              void* d_out, int out_size, void* d_ws, size_t ws_size,
                              hipStream_t stream) {
    // d_in[0]: cdr3_features [4,2048,1] fp32 — mathematically unused (softmax
    //          row-shift invariance cancels the Q2 term).
    // d_in[1]: all_atom_features [4,8192,1] fp32.
    const float* all_atom = (const float*)d_in[1];
    float* out = (float*)d_out;                      // out_size == 4 (B=4)

    InvariantCrossAttention_39582418600293_kernel<<<4, ICA_BLOCK, 0, stream>>>(all_atom, out);
}